// Round 5
// baseline (509.620 us; speedup 1.0000x reference)
//
#include <hip/hip_runtime.h>
#include <stdint.h>

// TemporalAttention: windowed causal attention, B=16 T=4096 C=512 H=8 hd=64 W=128
// R8: re-ranked targets from the top-5 cutoff (attn<140, proj<140, both ~140):
//  (a) qkv_gemm: R4/R7 verbatim (stable 141us, FETCH 52MB).
//  (b) proj_gemm: rebuilt as m97-style 128x128 tile, 256 thr, 32KB LDS ->
//      4-5 blocks/CU (implicit wave overlap), 2048 blocks XCD-chunked.
//      R4's 1-block/CU 8-wave lockstep was ~243 TF effective on 34 GF.
//  (c) attn: V never staged to LDS -- B-fragments read straight from vT
//      (layout matches fragment addressing; L2/L3-resident). LDS 48->32KB
//      (K 16KB + Pext 16KB, P overlays) -> 4 blocks/CU, 1024 fewer staging
//      granules per block.
//  (d) x-cast: 2 float4 per thread, single 16B store (was 8B stores).
// Workspace layout (bytes):
//   x_bf16    @ 0          : 67108864   (65536 x 512 bf16)
//   q_ws      @ 67108864   : 67108864   (4096 tiles x 128 x 64 bf16)
//   k_ws      @ 134217728  : 67108864   (4096 tiles x 128 x 64 bf16)
//   vT_ws     @ 201326592  : 67108864   (512 win x 8 h x 64 d x 128 t bf16)
//   attn_ws   @ 268435456  : 67108864   (65536 x 512 bf16)
//   wqkv_bf   @ 335544320  : 1572864
//   wproj_bf  @ 337117184  : 524288

typedef unsigned short ushort_t;
typedef __attribute__((ext_vector_type(8))) short short8;
typedef __attribute__((ext_vector_type(8))) unsigned short us8;
typedef __attribute__((ext_vector_type(4))) float f32x4;
typedef __attribute__((ext_vector_type(4))) float f4v;
typedef __attribute__((ext_vector_type(4))) unsigned short us4;

static __device__ __forceinline__ unsigned short f2bf(float f) {
  unsigned int u = __float_as_uint(f);
  u += 0x7FFFu + ((u >> 16) & 1u);   // RNE
  return (unsigned short)(u >> 16);
}

static __device__ __forceinline__ void gl_lds16(const ushort_t* g, ushort_t* l) {
  __builtin_amdgcn_global_load_lds(
      (const __attribute__((address_space(1))) void*)g,
      (__attribute__((address_space(3))) void*)l, 16, 0, 0);
}

// ---------------- cast fp32 -> bf16 (2x float4 in, one 16B store out) ----------------
__global__ __launch_bounds__(256) void cast_f32_bf16(const float* __restrict__ in,
                                                     ushort_t* __restrict__ out, int n8) {
  int i = blockIdx.x * 256 + threadIdx.x;
  if (i >= n8) return;
  f4v v0 = ((const f4v*)in)[2 * i];
  f4v v1 = ((const f4v*)in)[2 * i + 1];
  us8 o;
  o[0] = f2bf(v0.x); o[1] = f2bf(v0.y); o[2] = f2bf(v0.z); o[3] = f2bf(v0.w);
  o[4] = f2bf(v1.x); o[5] = f2bf(v1.y); o[6] = f2bf(v1.z); o[7] = f2bf(v1.w);
  ((us8*)out)[i] = o;
}

// ---------------- QKV GEMM (R4 schedule, measured 141us; R7 blocked epilogue) ----------------
// BM=256 BN=128 BK=64, 512 thr (8 waves, 4m x 2n). Ring-3 LDS (144KB),
// counted vmcnt(6), one barrier per K-step, setprio around MFMA cluster.
__global__ __launch_bounds__(512, 2) void qkv_gemm(const ushort_t* __restrict__ A,
                                                   const ushort_t* __restrict__ B,
                                                   ushort_t* __restrict__ q_ws,
                                                   ushort_t* __restrict__ k_ws,
                                                   ushort_t* __restrict__ vT) {
  __shared__ __align__(16) ushort_t smem[3 * 24576];   // 144 KB
  const int tid = threadIdx.x;
  const int lane = tid & 63;
  const int wv = tid >> 6;
  const int wr = wv >> 1, wc = wv & 1;
  const int lr = lane & 15;
  const int lg = lane >> 4;

  // XCD-chunked n-fastest decode: 3072 blocks, 8 XCDs, 384/chunk, 12 n-tiles.
  const int bid = blockIdx.x;
  const int wg = (bid & 7) * 384 + (bid >> 3);
  const int nb = wg % 12;
  const int mb = wg / 12;
  const int m0 = mb << 8;
  const int n0 = nb << 7;

  const int srow = tid >> 3;                    // 0..63
  const int ssw  = (((tid & 7) ^ (srow & 7)) << 3);
  const ushort_t* gA = A + (size_t)(m0 + srow) * 512 + ssw;
  const ushort_t* gB = B + (size_t)(n0 + srow) * 512 + ssw;

  f32x4 acc[4][4] = {};

  auto STAGE = [&](int t, int q) {
    ushort_t* Ab = smem + q * 24576;
    ushort_t* Bb = Ab + 16384;
    const int kk = t << 6;
#pragma unroll
    for (int r = 0; r < 4; ++r)
      gl_lds16(gA + (size_t)(r * 64) * 512 + kk, Ab + (r * 512 + wv * 64) * 8);
#pragma unroll
    for (int r = 0; r < 2; ++r)
      gl_lds16(gB + (size_t)(r * 64) * 512 + kk, Bb + (r * 512 + wv * 64) * 8);
  };

  STAGE(0, 0);
  STAGE(1, 1);
  asm volatile("s_waitcnt vmcnt(6)" ::: "memory");
  __builtin_amdgcn_s_barrier();

#pragma unroll
  for (int t = 0; t < 8; ++t) {
    const ushort_t* Ab = smem + (t % 3) * 24576;
    const ushort_t* Bb = Ab + 16384;
    short8 a[4][2], b[4][2];
#pragma unroll
    for (int ks = 0; ks < 2; ++ks) {
      const int co = ((((ks << 2) | lg) ^ (lr & 7)) << 3);
#pragma unroll
      for (int mi = 0; mi < 4; ++mi)
        a[mi][ks] = *(const short8*)(Ab + (wr * 64 + mi * 16 + lr) * 64 + co);
#pragma unroll
      for (int ni = 0; ni < 4; ++ni)
        b[ni][ks] = *(const short8*)(Bb + (wc * 64 + ni * 16 + lr) * 64 + co);
    }
    if (t + 2 < 8) STAGE(t + 2, (t + 2) % 3);
    if (t < 7) {
      if (t + 2 < 8) asm volatile("s_waitcnt vmcnt(6)" ::: "memory");
      else           asm volatile("s_waitcnt vmcnt(0)" ::: "memory");
      asm volatile("s_waitcnt lgkmcnt(0)" ::: "memory");
      __builtin_amdgcn_s_barrier();
    }
    __builtin_amdgcn_s_setprio(1);
#pragma unroll
    for (int ks = 0; ks < 2; ++ks)
#pragma unroll
      for (int mi = 0; mi < 4; ++mi)
#pragma unroll
        for (int ni = 0; ni < 4; ++ni)
          acc[mi][ni] = __builtin_amdgcn_mfma_f32_16x16x32_bf16(a[mi][ks], b[ni][ks], acc[mi][ni], 0, 0, 0);
    __builtin_amdgcn_s_setprio(0);
  }

  // Epilogue. C frag layout: col=lane&15, row=(lane>>4)*4+reg.
  const int lg4 = lg << 2;
  if (n0 < 1024) {
    // Q (n0<512) or K (512<=n0<1024) -> blocked [win*8+h][128][64]
    ushort_t* dst = (n0 < 512) ? q_ws : k_ws;
    const int cbase = (n0 < 512) ? n0 : (n0 - 512);
#pragma unroll
    for (int mi = 0; mi < 4; ++mi) {
      const int rr0 = wr * 64 + mi * 16 + lg4;         // 0..255 within block
#pragma unroll
      for (int ni = 0; ni < 4; ++ni) {
        const int c = cbase + wc * 64 + ni * 16 + lr;  // 0..511
        const int h = c >> 6, d = c & 63;
#pragma unroll
        for (int rg = 0; rg < 4; ++rg) {
          const int rr = rr0 + rg;
          const int win = (m0 >> 7) + (rr >> 7);
          dst[(size_t)(win * 8 + h) * 8192 + (rr & 127) * 64 + d] = f2bf(acc[mi][ni][rg]);
        }
      }
    }
  } else {
    const int winb = (m0 >> 7) + (wr >> 1);     // 2 windows per 256-row block
    const int t0b = (wr & 1) * 64;
#pragma unroll
    for (int mi = 0; mi < 4; ++mi) {
      const int t0 = t0b + mi * 16 + lg4;
#pragma unroll
      for (int ni = 0; ni < 4; ++ni) {
        const int c = n0 - 1024 + wc * 64 + ni * 16 + lr;  // 0..511
        const int h = c >> 6, d = c & 63;
        us4 o;
        o.x = f2bf(acc[mi][ni][0]); o.y = f2bf(acc[mi][ni][1]);
        o.z = f2bf(acc[mi][ni][2]); o.w = f2bf(acc[mi][ni][3]);
        *(us4*)(vT + (size_t)((winb * 8 + h) * 64 + d) * 128 + t0) = o;
      }
    }
  }
}

// ---------------- fused windowed causal attention ----------------
// LDS 32KB: K [128][64] @0 (8192 el), Pext @8192 (8192 el).
// P[128][128] overlays: rows 0-63 in K region, rows 64-127 in Pext.
// paddr(row,col) = (row&63)*128 + ((row>>6)<<13) + swizzled col.
// V is NOT staged: B-fragments read straight from vT (global, L2/L3-hot).
__global__ __launch_bounds__(256) void attn_kernel(const ushort_t* __restrict__ q_ws,
                                                   const ushort_t* __restrict__ k_ws,
                                                   const ushort_t* __restrict__ vT,
                                                   ushort_t* __restrict__ attn_out) {
  __shared__ __align__(16) ushort_t smem[16384];
  ushort_t* ks_ = smem;

  const int tid = threadIdx.x;
  const int lane = tid & 63;
  const int wv = tid >> 6;
  const int win = blockIdx.x >> 3;
  const int h = blockIdx.x & 7;
  const int lr = lane & 15;
  const int lg = lane >> 4;
  const int lg4 = lg << 2;
  const int sw = lr & 7;

  const size_t base = (size_t)(win * 8 + h) * 8192;

  // --- async stage K [128][64] (pre-swizzled source, linear dest) ---
#pragma unroll
  for (int i = 0; i < 4; ++i) {
    const int g = i * 256 + tid;                 // granule 0..1023
    const int t = g >> 3, ch = g & 7;
    gl_lds16(k_ws + base + t * 64 + ((ch ^ (t & 7)) << 3), ks_ + g * 8);
  }

  const int rt[2] = {wv, 7 - wv};                // rt[1] > rt[0]

  // --- Q fragments straight from global (contiguous blocked layout) ---
  short8 aq[2][2];
#pragma unroll
  for (int mi = 0; mi < 2; ++mi)
#pragma unroll
    for (int ks = 0; ks < 2; ++ks)
      aq[mi][ks] = *(const short8*)(q_ws + base + (size_t)(rt[mi] * 16 + lr) * 64 + ks * 32 + lg * 8);

  __syncthreads();   // staging landed (syncthreads drains vmcnt)

  // --- S = q k^T, causal col tiles only ---
  f32x4 sacc[2][8] = {};
#pragma unroll
  for (int ks2 = 0; ks2 < 2; ++ks2) {
    const int co = ((((ks2 << 2) | lg) ^ sw) << 3);
#pragma unroll
    for (int ni = 0; ni < 8; ++ni) {
      if (ni <= rt[1]) {
        short8 b = *(const short8*)(ks_ + (ni * 16 + lr) * 64 + co);
        if (ni <= rt[0])
          sacc[0][ni] = __builtin_amdgcn_mfma_f32_16x16x32_bf16(aq[0][ks2], b, sacc[0][ni], 0, 0, 0);
        sacc[1][ni] = __builtin_amdgcn_mfma_f32_16x16x32_bf16(aq[1][ks2], b, sacc[1][ni], 0, 0, 0);
      }
    }
  }

  __syncthreads();  // all waves done reading K before P overlays the K region

  // --- exp (unshifted; scores bounded ~|2|) + causal mask; write P bf16 swizzled ---
  const float C = 0.125f * 1.44269504f;   // scale * log2(e)
#pragma unroll
  for (int mi = 0; mi < 2; ++mi) {
    const int r = rt[mi];
    const int rb = r * 16;
#pragma unroll
    for (int ni = 0; ni < 8; ++ni) {
      if (ni <= r) {
#pragma unroll
        for (int rg = 0; rg < 4; ++rg) {
          const int row = rb + lg4 + rg;
          const int col = ni * 16 + lr;
          float e = __builtin_exp2f(sacc[mi][ni][rg] * C);
          e = (col <= row) ? e : 0.0f;
          smem[(row & 63) * 128 + ((row >> 6) << 13) +
               ((((col >> 3) ^ (row & 7)) << 3) | (col & 7))] = f2bf(e);
        }
      }
    }
    if (!(r & 1)) {  // even tile: PV k32-step covers tile r+1 -> zero it
      const int col = (r + 1) * 16 + lr;
#pragma unroll
      for (int rg = 0; rg < 4; ++rg) {
        const int row = rb + lg4 + rg;
        smem[(row & 63) * 128 + ((row >> 6) << 13) +
             ((((col >> 3) ^ (row & 7)) << 3) | (col & 7))] = 0;
      }
    }
  }
  // each wave reads back only the P rows it wrote -> no barrier needed

  // --- O = P V + ones-column row-sum; V frags direct from global ---
  const short one_bf = (short)0x3F80;
  short8 ones;
#pragma unroll
  for (int j = 0; j < 8; ++j) ones[j] = (lr == 0) ? one_bf : (short)0;

  const int r0 = rt[0] * 16 + lr;   // P row read by this lane, tile 0
  const int r1 = rt[1] * 16 + lr;   // tile 1
  const ushort_t* p0 = smem + (r0 & 63) * 128 + ((r0 >> 6) << 13);
  const ushort_t* p1 = smem + (r1 & 63) * 128 + ((r1 >> 6) << 13);
  const ushort_t* vg = vT + base;   // [64 d][128 t] linear

  f32x4 oacc[2][4] = {};
  f32x4 sm[2] = {};
#pragma unroll
  for (int ks2 = 0; ks2 < 4; ++ks2) {
    const int co = ((((ks2 << 2) | lg) ^ sw) << 3);      // swizzled (LDS P)
    const int cv = (((ks2 << 2) | lg) << 3);             // linear (global V)
    if (ks2 <= (rt[1] >> 1)) {
      short8 b[4];
#pragma unroll
      for (int nd = 0; nd < 4; ++nd)
        b[nd] = *(const short8*)(vg + (size_t)(nd * 16 + lr) * 128 + cv);
      short8 a1 = *(const short8*)(p1 + co);
#pragma unroll
      for (int nd = 0; nd < 4; ++nd)
        oacc[1][nd] = __builtin_amdgcn_mfma_f32_16x16x32_bf16(a1, b[nd], oacc[1][nd], 0, 0, 0);
      sm[1] = __builtin_amdgcn_mfma_f32_16x16x32_bf16(a1, ones, sm[1], 0, 0, 0);
      if (ks2 <= (rt[0] >> 1)) {
        short8 a0 = *(const short8*)(p0 + co);
#pragma unroll
        for (int nd = 0; nd < 4; ++nd)
          oacc[0][nd] = __builtin_amdgcn_mfma_f32_16x16x32_bf16(a0, b[nd], oacc[0][nd], 0, 0, 0);
        sm[0] = __builtin_amdgcn_mfma_f32_16x16x32_bf16(a0, ones, sm[0], 0, 0, 0);
      }
    }
  }

  // --- epilogue: rs = 1/rowsum (broadcast from lr==0 lane of each group) ---
  const int src = lane & 48;
  const size_t obase = (size_t)win * 128 * 512 + h * 64;
#pragma unroll
  for (int mi = 0; mi < 2; ++mi) {
    const int rb = rt[mi] * 16;
    float rsv[4];
#pragma unroll
    for (int rg = 0; rg < 4; ++rg)
      rsv[rg] = 1.0f / __shfl(sm[mi][rg], src);
#pragma unroll
    for (int nd = 0; nd < 4; ++nd)
#pragma unroll
      for (int rg = 0; rg < 4; ++rg) {
        const int row = rb + lg4 + rg;
        const int col = nd * 16 + lr;
        attn_out[obase + (size_t)row * 512 + col] = f2bf(oacc[mi][nd][rg] * rsv[rg]);
      }
  }
}

// ---------------- proj GEMM: m97-style 128x128 tile, 256 thr, 32KB LDS ----------------
// 2048 blocks XCD-chunked (256/XCD), 4 n-tiles fastest. 4-5 blocks/CU ->
// implicit wave-level overlap replaces R4's 1-block/CU lockstep.
__global__ __launch_bounds__(256) void proj_gemm(const ushort_t* __restrict__ A,
                                                 const ushort_t* __restrict__ B,
                                                 const float* __restrict__ bias,
                                                 float* __restrict__ out) {
  __shared__ __align__(16) ushort_t As[128 * 64];
  __shared__ __align__(16) ushort_t Bs[128 * 64];
  const int tid = threadIdx.x;
  const int lane = tid & 63;
  const int wv = tid >> 6;
  const int wr = wv >> 1, wc = wv & 1;
  const int lr = lane & 15;
  const int lg = lane >> 4;
  const int sw = lr & 7;

  // XCD-chunked n-fastest decode: 2048 blocks, 8 XCDs, 256/chunk, 4 n-tiles.
  const int bid = blockIdx.x;
  const int wg = (bid & 7) * 256 + (bid >> 3);
  const int nb = wg & 3;
  const int mb = wg >> 2;
  const int m0 = mb << 7;
  const int n0 = nb << 7;

  f32x4 acc[4][4] = {};

  const int grow = tid >> 3;                               // 0..31
  const int gcol = (((tid & 7) ^ (grow & 7)) << 3);        // swizzled chunk fetch
  const ushort_t* gA = A + (size_t)(m0 + grow) * 512 + gcol;
  const ushort_t* gB = B + (size_t)(n0 + grow) * 512 + gcol;

  for (int kk = 0; kk < 512; kk += 64) {
#pragma unroll
    for (int r = 0; r < 4; ++r) {
      gl_lds16(gA + (size_t)(r * 32) * 512 + kk, As + (size_t)(r * 256 + wv * 64) * 8);
      gl_lds16(gB + (size_t)(r * 32) * 512 + kk, Bs + (size_t)(r * 256 + wv * 64) * 8);
    }
    __syncthreads();
#pragma unroll
    for (int ks = 0; ks < 2; ++ks) {
      const int co = ((((ks << 2) | lg) ^ sw) << 3);
      short8 a[4], b[4];
#pragma unroll
      for (int mi = 0; mi < 4; ++mi)
        a[mi] = *(const short8*)(As + (wr * 64 + mi * 16 + lr) * 64 + co);
#pragma unroll
      for (int ni = 0; ni < 4; ++ni)
        b[ni] = *(const short8*)(Bs + (wc * 64 + ni * 16 + lr) * 64 + co);
#pragma unroll
      for (int mi = 0; mi < 4; ++mi)
#pragma unroll
        for (int ni = 0; ni < 4; ++ni)
          acc[mi][ni] = __builtin_amdgcn_mfma_f32_16x16x32_bf16(a[mi], b[ni], acc[mi][ni], 0, 0, 0);
    }
    __syncthreads();
  }

  const int lg4 = lg << 2;
#pragma unroll
  for (int mi = 0; mi < 4; ++mi) {
    const int rbase = m0 + wr * 64 + mi * 16 + lg4;
#pragma unroll
    for (int ni = 0; ni < 4; ++ni) {
      const int col = n0 + wc * 64 + ni * 16 + lr;
      const float bv = bias[col];
#pragma unroll
      for (int rg = 0; rg < 4; ++rg)
        out[(size_t)(rbase + rg) * 512 + col] = acc[mi][ni][rg] + bv;
    }
  }
}

extern "C" void kernel_launch(void* const* d_in, const int* in_sizes, int n_in,
                              void* d_out, int out_size, void* d_ws, size_t ws_size,
                              hipStream_t stream) {
  const float* x      = (const float*)d_in[0];
  const float* w_qkv  = (const float*)d_in[1];
  const float* w_proj = (const float*)d_in[2];
  const float* b_proj = (const float*)d_in[3];
  float* out = (float*)d_out;

  char* ws = (char*)d_ws;
  ushort_t* x_bf     = (ushort_t*)(ws);
  ushort_t* q_ws     = (ushort_t*)(ws + 67108864);
  ushort_t* k_ws     = (ushort_t*)(ws + 134217728);
  ushort_t* vT_ws    = (ushort_t*)(ws + 201326592);
  ushort_t* attn_ws  = (ushort_t*)(ws + 268435456);
  ushort_t* wqkv_bf  = (ushort_t*)(ws + 335544320);
  ushort_t* wproj_bf = (ushort_t*)(ws + 337117184);

  cast_f32_bf16<<<16384, 256, 0, stream>>>(x, x_bf, 4194304);
  cast_f32_bf16<<<384, 256, 0, stream>>>(w_qkv, wqkv_bf, 98304);
  cast_f32_bf16<<<128, 256, 0, stream>>>(w_proj, wproj_bf, 32768);

  qkv_gemm<<<3072, 512, 0, stream>>>(x_bf, wqkv_bf, q_ws, k_ws, vT_ws);
  attn_kernel<<<4096, 256, 0, stream>>>(q_ws, k_ws, vT_ws, attn_ws);
  proj_gemm<<<2048, 256, 0, stream>>>(attn_ws, wproj_bf, b_proj, out);
}